// Round 12
// baseline (3993.366 us; speedup 1.0000x reference)
//
#include <hip/hip_runtime.h>

#define HID 15
#define NG  60      // 4*HID
#define DIM 64
#define T2  2048
#define NLAY 4
#define BSZ 512

// bf16 RNE rounding — PROVEN bit-trick (rounds 6/7). v_cvt_pk_bf16_f32
// produced NaNs twice (even battery-guarded) — do not revisit.
__device__ __forceinline__ float bfr(float x) {
    unsigned u = __float_as_uint(x);
    u = (u + 0x7FFFu + ((u >> 16) & 1u)) & 0xFFFF0000u;
    return __uint_as_float(u);
}
// one bf16-rounded multiply-accumulate term: acc = bf(acc + bf(a*b))
#define CH(acc, a, b) acc = bfr(acc + bfr((a) * (b)))

__device__ __forceinline__ float tanh_np(float z) {
    const float e = __expf(-2.0f * z);
    return bfr((1.0f - e) / (1.0f + e));
}
__device__ __forceinline__ float sig_np(float z) {
    const float e   = bfr(__expf(-z));
    const float den = bfr(1.0f + e);
    return bfr(1.0f / den);
}
__device__ __forceinline__ float b2f(unsigned short b) {
    return __uint_as_float(((unsigned)b) << 16);
}

// ============ Phase 1: layer-0 input projection (R7 pipelined) ============
// Issue-saturated at 8 waves/SIMD (~470us floor — 1.05M rows x 532 instr).
__global__ __launch_bounds__(256, 1)
void proj0(const float* __restrict__ emb,
           const int*   __restrict__ lengths,
           const float* __restrict__ Wih0,
           unsigned short* __restrict__ pa)
{
    const int wave = threadIdx.x >> 6;
    const int lane = threadIdx.x & 63;
    const int g    = (lane < NG) ? lane : (NG - 1);

    __shared__ __align__(16) float xrow[4][64];

    float wx[DIM];
    #pragma unroll
    for (int q = 0; q < 16; ++q) {
        float4 w = *(const float4*)(Wih0 + g*DIM + 4*q);
        wx[4*q+0] = bfr(w.x); wx[4*q+1] = bfr(w.y);
        wx[4*q+2] = bfr(w.z); wx[4*q+3] = bfr(w.w);
    }

    const int nrows  = BSZ * T2;
    const int stride = gridDim.x * 4;
    const int r0     = blockIdx.x * 4 + wave;

    float x_reg = 0.0f;
    if (r0 < nrows) x_reg = emb[(size_t)r0 * DIM + lane];   // prime pipeline

    for (int r = r0; r < nrows; r += stride) {
        const int rn = r + stride;                 // next row's load first
        float xnext = 0.0f;
        if (rn < nrows) xnext = emb[(size_t)rn * DIM + lane];

        xrow[wave][lane] = bfr(x_reg);             // in-wave write->read

        const int b = r >> 11;                     // r / T2 (wave-uniform)
        const int t = r & (T2 - 1);
        if (t < lengths[b]) {
            const float4* xv = (const float4*)xrow[wave];
            float acc = 0.0f;
            #pragma unroll
            for (int q = 0; q < 16; ++q) {
                float4 v = xv[q];
                CH(acc, v.x, wx[4*q+0]);
                CH(acc, v.y, wx[4*q+1]);
                CH(acc, v.z, wx[4*q+2]);
                CH(acc, v.w, wx[4*q+3]);
            }
            if (lane < NG)
                pa[(size_t)r * NG + g] = (unsigned short)(__float_as_uint(acc) >> 16);
        }
        x_reg = xnext;
    }
}

// ====== Phase 2: layer-pipelined recurrence, TWO sequences per wave ======
// Wave l = layer l for seqs sA=2*blockIdx and sB=sA+1. Four independent
// CH chains + two activation/cell chains per superstep -> in-wave ILP fills
// dependency stalls WITHOUT barrier coupling (R10/R11 lesson: TLP across a
// barrier pays the slowest wave's latency every superstep).
// Sorted-descending lengths make lenB<=lenA and pairs finish together, but
// correctness uses per-seq predicates only (loads clamped in-bounds,
// h_lds/out writes gated) — no reliance on input ordering.
// Per-gate op sequence identical to rounds 6/7 -> bit-identical output.
__global__ __launch_bounds__(256, 1)
void lstm4_pipe2(const int* __restrict__ lengths,
                 const unsigned short* __restrict__ pa,
                 const float* __restrict__ Wihr,
                 const float* __restrict__ Whh,
                 const float* __restrict__ bih,
                 const float* __restrict__ bhh,
                 float* __restrict__ out)
{
    const int sA   = blockIdx.x * 2;
    const int sB   = sA + 1;
    const int wave = threadIdx.x >> 6;     // = layer index
    const int lane = threadIdx.x & 63;
    const int g    = (lane < NG) ? lane : (NG - 1);

    __shared__ __align__(16) float h_lds[2][2][NLAY][16];  // [seq][parity][layer][h]

    const int l = wave;
    float wr[16], wi[16];                  // shared by both seqs (same layer)
    #pragma unroll
    for (int j = 0; j < HID; ++j) wr[j] = bfr(Whh[(l*NG + g)*HID + j]);
    wr[15] = 0.0f;
    if (l > 0) {
        #pragma unroll
        for (int j = 0; j < HID; ++j) wi[j] = bfr(Wihr[((l-1)*NG + g)*HID + j]);
        wi[15] = 0.0f;
    } else {
        #pragma unroll
        for (int j = 0; j < 16; ++j) wi[j] = 0.0f;
    }
    const float bias_ = bfr(bfr(bih[l*NG + g]) + bfr(bhh[l*NG + g]));

    int lenA = lengths[sA]; lenA = lenA < 1 ? 1 : (lenA > T2 ? T2 : lenA);
    int lenB = lengths[sB]; lenB = lenB < 1 ? 1 : (lenB > T2 ? T2 : lenB);
    const unsigned short* pasA = pa + (size_t)sA * T2 * NG;
    const unsigned short* pasB = pa + (size_t)sB * T2 * NG;

    float cA = 0.0f, cB = 0.0f;
    float hsA[HID], hsB[HID];              // readlane -> wave-uniform (SGPR)
    #pragma unroll
    for (int j = 0; j < HID; ++j) { hsA[j] = 0.0f; hsB[j] = 0.0f; }

    unsigned short panbA = 0, panbB = 0;
    if (l == 0) { panbA = pasA[g]; panbB = pasB[g]; }   // t=0 rows

    const bool tg  = (lane >= 30 && lane < 45);
    const int lmax = (lenA > lenB) ? lenA : lenB;
    const int nss  = lmax + NLAY - 1;

    for (int k = 0; k < nss; ++k) {
        const int t  = k - l;
        const bool vA = (t >= 0) & (t < lenA);
        const bool vB = (t >= 0) & (t < lenB);
        if (vA | vB) {                     // wave-uniform
            float aiA = 0.0f, arA = 0.0f, aiB = 0.0f, arB = 0.0f;
            float hvA[16], hvB[16];

            if (l > 0) {                   // issue LDS reads first
                const float4* hpA = (const float4*)h_lds[0][t & 1][l - 1];
                const float4* hpB = (const float4*)h_lds[1][t & 1][l - 1];
                *(float4*)&hvA[0]  = hpA[0]; *(float4*)&hvA[4]  = hpA[1];
                *(float4*)&hvA[8]  = hpA[2]; *(float4*)&hvA[12] = hpA[3];
                *(float4*)&hvB[0]  = hpB[0]; *(float4*)&hvB[4]  = hpB[1];
                *(float4*)&hvB[8]  = hpB[2]; *(float4*)&hvB[12] = hpB[3];
            }

            // recurrent chains (register/SGPR inputs) cover the LDS latency
            #pragma unroll
            for (int j = 0; j < HID; ++j) CH(arA, hsA[j], wr[j]);
            #pragma unroll
            for (int j = 0; j < HID; ++j) CH(arB, hsB[j], wr[j]);

            if (l == 0) {
                aiA = b2f(panbA);  aiB = b2f(panbB);
                const int tnA = (t + 1 < lenA) ? (t + 1) : (lenA - 1);  // clamp
                const int tnB = (t + 1 < lenB) ? (t + 1) : (lenB - 1);
                panbA = pasA[(size_t)tnA * NG + g];   // prefetch, 1 superstep
                panbB = pasB[(size_t)tnB * NG + g];
            } else {
                #pragma unroll
                for (int j = 0; j < HID; ++j) CH(aiA, hvA[j], wi[j]);
                #pragma unroll
                for (int j = 0; j < HID; ++j) CH(aiB, hvB[j], wi[j]);
            }

            const float zA = bfr(bfr(aiA + arA) + bias_);
            const float zB = bfr(bfr(aiB + arB) + bias_);
            const float aA = tg ? tanh_np(zA) : sig_np(zA);
            const float aB = tg ? tanh_np(zB) : sig_np(zB);

            const float fvA = __shfl(aA, (lane + 15) & 63);
            const float gvA = __shfl(aA, (lane + 30) & 63);
            const float ovA = __shfl(aA, (lane + 45) & 63);
            const float fvB = __shfl(aB, (lane + 15) & 63);
            const float gvB = __shfl(aB, (lane + 30) & 63);
            const float ovB = __shfl(aB, (lane + 45) & 63);

            const float cnA = bfr(bfr(fvA * cA) + bfr(aA * gvA));
            const float cnB = bfr(bfr(fvB * cB) + bfr(aB * gvB));
            cA = cnA; cB = cnB;
            const float hnA = bfr(ovA * tanh_np(cnA));
            const float hnB = bfr(ovB * tanh_np(cnB));

            #pragma unroll
            for (int j = 0; j < HID; ++j) {
                hsA[j] = __uint_as_float(__builtin_amdgcn_readlane(__float_as_uint(hnA), j));
                hsB[j] = __uint_as_float(__builtin_amdgcn_readlane(__float_as_uint(hnB), j));
            }

            if (vA && lane < HID) h_lds[0][t & 1][l][lane] = hnA;
            if (vB && lane < HID) h_lds[1][t & 1][l][lane] = hnB;
            if (l == NLAY - 1 && lane < HID) {
                if (t == lenA - 1) out[sA * HID + lane] = hnA;
                if (t == lenB - 1) out[sB * HID + lane] = hnB;
            }
        }
        __syncthreads();                   // end of superstep
    }
}

// ============ Fallback (round-6, passing): used if ws too small ============
__global__ __launch_bounds__(64, 1)
void lstm4_bf16np(const float* __restrict__ emb,
                  const int*   __restrict__ lengths,
                  const float* __restrict__ Wih0,
                  const float* __restrict__ Wihr,
                  const float* __restrict__ Whh,
                  const float* __restrict__ bih,
                  const float* __restrict__ bhh,
                  float* __restrict__ out)
{
    const int s    = blockIdx.x;
    const int lane = threadIdx.x;
    const int g    = (lane < NG) ? lane : (NG - 1);

    __shared__ __align__(16) float x_lds[DIM];
    __shared__ __align__(16) float h_lds[NLAY][16];

    float wx[DIM];
    #pragma unroll
    for (int q = 0; q < DIM/4; ++q) {
        float4 w = *(const float4*)(Wih0 + g*DIM + 4*q);
        wx[4*q+0] = bfr(w.x); wx[4*q+1] = bfr(w.y);
        wx[4*q+2] = bfr(w.z); wx[4*q+3] = bfr(w.w);
    }
    float wr[NLAY][16]; float wi[NLAY-1][16]; float bias[NLAY];
    #pragma unroll
    for (int l = 0; l < NLAY; ++l) {
        #pragma unroll
        for (int j = 0; j < HID; ++j) wr[l][j] = bfr(Whh[(l*NG + g)*HID + j]);
        wr[l][15] = 0.0f;
        bias[l] = bfr(bfr(bih[l*NG + g]) + bfr(bhh[l*NG + g]));
    }
    #pragma unroll
    for (int l = 0; l < NLAY-1; ++l) {
        #pragma unroll
        for (int j = 0; j < HID; ++j) wi[l][j] = bfr(Wihr[(l*NG + g)*HID + j]);
        wi[l][15] = 0.0f;
    }
    if (lane < 16) {
        #pragma unroll
        for (int l = 0; l < NLAY; ++l) h_lds[l][lane] = 0.0f;
    }
    float c[NLAY] = {0.0f, 0.0f, 0.0f, 0.0f};
    int len = lengths[s];
    len = len < 1 ? 1 : (len > T2 ? T2 : len);
    const float* xb = emb + (size_t)s * T2 * DIM;
    x_lds[lane] = bfr(xb[lane]);
    __syncthreads();
    const bool tg = (lane >= 30 && lane < 45);
    const float4* x4 = (const float4*)x_lds;
    float hout = 0.0f;
    for (int t = 0; t < len; ++t) {
        const int tn = (t + 1 < len) ? (t + 1) : t;
        const float xn = bfr(xb[(size_t)tn * DIM + lane]);
        #pragma unroll
        for (int l = 0; l < NLAY; ++l) {
            float a_in = 0.0f;
            if (l == 0) {
                #pragma unroll
                for (int q = 0; q < 16; ++q) {
                    float4 v = x4[q];
                    CH(a_in, v.x, wx[4*q+0]); CH(a_in, v.y, wx[4*q+1]);
                    CH(a_in, v.z, wx[4*q+2]); CH(a_in, v.w, wx[4*q+3]);
                }
            } else {
                const float4* hp = (const float4*)h_lds[l-1];
                float hv[16];
                *(float4*)&hv[0]  = hp[0]; *(float4*)&hv[4]  = hp[1];
                *(float4*)&hv[8]  = hp[2]; *(float4*)&hv[12] = hp[3];
                #pragma unroll
                for (int j = 0; j < HID; ++j) CH(a_in, hv[j], wi[l-1][j]);
            }
            float a_rec = 0.0f;
            {
                const float4* hc = (const float4*)h_lds[l];
                float hv[16];
                *(float4*)&hv[0]  = hc[0]; *(float4*)&hv[4]  = hc[1];
                *(float4*)&hv[8]  = hc[2]; *(float4*)&hv[12] = hc[3];
                #pragma unroll
                for (int j = 0; j < HID; ++j) CH(a_rec, hv[j], wr[l][j]);
            }
            const float z = bfr(bfr(a_in + a_rec) + bias[l]);
            const float a = tg ? tanh_np(z) : sig_np(z);
            const float fv = __shfl(a, (lane + 15) & 63);
            const float gv = __shfl(a, (lane + 30) & 63);
            const float ov = __shfl(a, (lane + 45) & 63);
            const float cn = bfr(bfr(fv * c[l]) + bfr(a * gv));
            c[l] = cn;
            const float hn = bfr(ov * tanh_np(cn));
            if (lane < HID) h_lds[l][lane] = hn;
            if (l == NLAY-1 && t == len-1) hout = hn;
        }
        x_lds[lane] = xn;
    }
    if (lane < HID) out[s * HID + lane] = hout;
}

extern "C" void kernel_launch(void* const* d_in, const int* in_sizes, int n_in,
                              void* d_out, int out_size, void* d_ws, size_t ws_size,
                              hipStream_t stream) {
    const float* emb     = (const float*)d_in[0];
    const int*   lengths = (const int*)  d_in[1];
    const float* Wih0    = (const float*)d_in[2];
    const float* Wihr    = (const float*)d_in[3];
    const float* Whh     = (const float*)d_in[4];
    const float* bih     = (const float*)d_in[5];
    const float* bhh     = (const float*)d_in[6];
    float* out = (float*)d_out;

    const size_t need = (size_t)BSZ * T2 * NG * sizeof(unsigned short);
    if (ws_size >= need) {
        unsigned short* pa = (unsigned short*)d_ws;
        proj0<<<2048, 256, 0, stream>>>(emb, lengths, Wih0, pa);
        lstm4_pipe2<<<BSZ/2, 256, 0, stream>>>(lengths, pa, Wihr, Whh, bih, bhh, out);
    } else {
        lstm4_bf16np<<<BSZ, 64, 0, stream>>>(emb, lengths, Wih0, Wihr, Whh, bih, bhh, out);
    }
}

// Round 13
// 2367.326 us; speedup vs baseline: 1.6869x; 1.6869x over previous
//
#include <hip/hip_runtime.h>

#define HID 15
#define NG  60      // 4*HID
#define DIM 64
#define T2  2048
#define NLAY 4
#define BSZ 512
#define DG  8       // supersteps per barrier group (layer skew depth)
#define RS  16      // h-ring slots = 2*DG

// bf16 RNE rounding — PROVEN bit-trick (rounds 6/7). v_cvt_pk_bf16_f32
// produced NaNs twice (even battery-guarded) — do not revisit.
__device__ __forceinline__ float bfr(float x) {
    unsigned u = __float_as_uint(x);
    u = (u + 0x7FFFu + ((u >> 16) & 1u)) & 0xFFFF0000u;
    return __uint_as_float(u);
}
// one bf16-rounded multiply-accumulate term: acc = bf(acc + bf(a*b))
#define CH(acc, a, b) acc = bfr(acc + bfr((a) * (b)))

__device__ __forceinline__ float tanh_np(float z) {
    const float e = __expf(-2.0f * z);
    return bfr((1.0f - e) / (1.0f + e));
}
__device__ __forceinline__ float sig_np(float z) {
    const float e   = bfr(__expf(-z));
    const float den = bfr(1.0f + e);
    return bfr(1.0f / den);
}
__device__ __forceinline__ float b2f(unsigned b) {
    return __uint_as_float(b << 16);
}

// ============ Phase 1: layer-0 projection, 2 rows per wave (ILP) ============
// Rows r=2p (b,t) and r+1 (b,t+1): two independent 64-link chains interleaved
// halve the dependent-add latency exposure. Per-row op order = rounds 6/7.
__global__ __launch_bounds__(256, 1)
void proj0(const float* __restrict__ emb,
           const int*   __restrict__ lengths,
           const float* __restrict__ Wih0,
           unsigned short* __restrict__ pa)
{
    const int wave = threadIdx.x >> 6;
    const int lane = threadIdx.x & 63;
    const int g    = (lane < NG) ? lane : (NG - 1);

    __shared__ __align__(16) float xrow[4][2][64];

    float wx[DIM];
    #pragma unroll
    for (int q = 0; q < 16; ++q) {
        float4 w = *(const float4*)(Wih0 + g*DIM + 4*q);
        wx[4*q+0] = bfr(w.x); wx[4*q+1] = bfr(w.y);
        wx[4*q+2] = bfr(w.z); wx[4*q+3] = bfr(w.w);
    }

    const int npairs = (BSZ * T2) / 2;
    const int stride = gridDim.x * 4;
    const int p0     = blockIdx.x * 4 + wave;

    float xr0 = 0.0f, xr1 = 0.0f;
    if (p0 < npairs) {                       // prime pipeline
        xr0 = emb[(size_t)(2*p0)     * DIM + lane];
        xr1 = emb[(size_t)(2*p0 + 1) * DIM + lane];
    }

    for (int p = p0; p < npairs; p += stride) {
        const int pn = p + stride;           // prefetch next pair first
        float xn0 = 0.0f, xn1 = 0.0f;
        if (pn < npairs) {
            xn0 = emb[(size_t)(2*pn)     * DIM + lane];
            xn1 = emb[(size_t)(2*pn + 1) * DIM + lane];
        }

        const int r   = 2 * p;
        const int b   = r >> 11;             // r / T2 (wave-uniform)
        const int t   = r & (T2 - 1);        // even; r+1 is (b, t+1)
        const int len = lengths[b];

        if (t < len) {                       // t>=len implies t+1>=len too
            xrow[wave][0][lane] = bfr(xr0);  // in-wave write->read (lgkmcnt)
            xrow[wave][1][lane] = bfr(xr1);
            const float4* xv0 = (const float4*)xrow[wave][0];
            const float4* xv1 = (const float4*)xrow[wave][1];
            float a0 = 0.0f, a1 = 0.0f;      // two independent chains
            #pragma unroll
            for (int q = 0; q < 16; ++q) {
                float4 u = xv0[q]; float4 v = xv1[q];
                CH(a0, u.x, wx[4*q+0]); CH(a1, v.x, wx[4*q+0]);
                CH(a0, u.y, wx[4*q+1]); CH(a1, v.y, wx[4*q+1]);
                CH(a0, u.z, wx[4*q+2]); CH(a1, v.z, wx[4*q+2]);
                CH(a0, u.w, wx[4*q+3]); CH(a1, v.w, wx[4*q+3]);
            }
            if (lane < NG) {
                pa[(size_t)r * NG + g] = (unsigned short)(__float_as_uint(a0) >> 16);
                if (t + 1 < len)
                    pa[(size_t)(r + 1) * NG + g] = (unsigned short)(__float_as_uint(a1) >> 16);
            }
        }
        xr0 = xn0; xr1 = xn1;
    }
}

// ====== Phase 2: deep-ring layer pipeline — barrier every DG supersteps ======
// Wave l processes t in [(grp-l)*DG, +DG) during barrier-group grp. h handoff
// via ring[l][t&15]: writer half and reader half are disjoint mod 16 (bases
// differ by DG=8), so ONE barrier per group orders everything. Waves slide
// freely within a group -> sibling waves fill each other's latency stalls
// (R7's per-superstep barrier re-synced jitter 2051x; now ~260x).
// Per-gate op sequence identical to rounds 6/7 -> bit-identical output.
__global__ __launch_bounds__(256, 1)
void lstm4_pipe(const int* __restrict__ lengths,
                const unsigned short* __restrict__ pa,
                const float* __restrict__ Wihr,
                const float* __restrict__ Whh,
                const float* __restrict__ bih,
                const float* __restrict__ bhh,
                float* __restrict__ out)
{
    const int s    = blockIdx.x;
    const int wave = threadIdx.x >> 6;     // = layer index l
    const int lane = threadIdx.x & 63;
    const int g    = (lane < NG) ? lane : (NG - 1);

    __shared__ __align__(16) float ring[NLAY-1][RS][16];   // layers 0..2 publish

    const int l = wave;
    float wr[16], wi[16];
    #pragma unroll
    for (int j = 0; j < HID; ++j) wr[j] = bfr(Whh[(l*NG + g)*HID + j]);
    wr[15] = 0.0f;
    if (l > 0) {
        #pragma unroll
        for (int j = 0; j < HID; ++j) wi[j] = bfr(Wihr[((l-1)*NG + g)*HID + j]);
        wi[15] = 0.0f;
    } else {
        #pragma unroll
        for (int j = 0; j < 16; ++j) wi[j] = 0.0f;
    }
    const float bias_ = bfr(bfr(bih[l*NG + g]) + bfr(bhh[l*NG + g]));

    int len = lengths[s];
    len = len < 1 ? 1 : (len > T2 ? T2 : len);
    const unsigned short* pas = pa + (size_t)s * T2 * NG;

    float c_ = 0.0f;
    float hs[HID];
    #pragma unroll
    for (int j = 0; j < HID; ++j) hs[j] = 0.0f;

    // pa group-prefetch, double-buffered 8-deep (wave 0 only)
    unsigned pan_c[DG], pan_n[DG];
    if (l == 0) {
        #pragma unroll
        for (int d = 0; d < DG; ++d) {
            const int tt = (d < len) ? d : (len - 1);
            pan_n[d] = pas[(size_t)tt * NG + g];
        }
    }

    const bool tg = (lane >= 30 && lane < 45);
    const int ngrp = (len + DG - 1) / DG;    // active groups per wave
    const int G    = ngrp + NLAY - 1;

    for (int grp = 0; grp < G; ++grp) {
        const int myg = grp - l;
        if (myg >= 0 && myg < ngrp) {        // wave-uniform
            const int t0 = myg * DG;

            if (l == 0) {                    // rotate buffers, prefetch next 8
                #pragma unroll
                for (int d = 0; d < DG; ++d) pan_c[d] = pan_n[d];
                #pragma unroll
                for (int d = 0; d < DG; ++d) {
                    int tt = t0 + DG + d; tt = (tt < len) ? tt : (len - 1);
                    pan_n[d] = pas[(size_t)tt * NG + g];
                }
            }

            #pragma unroll
            for (int d = 0; d < DG; ++d) {   // 8 supersteps, NO barrier inside
                const int t = t0 + d;
                if (t < len) {               // wave-uniform
                    float a_in = 0.0f, a_rec = 0.0f;
                    float hv[16];

                    if (l > 0) {             // issue LDS reads early
                        const float4* hp = (const float4*)ring[l-1][t & (RS-1)];
                        *(float4*)&hv[0]  = hp[0]; *(float4*)&hv[4]  = hp[1];
                        *(float4*)&hv[8]  = hp[2]; *(float4*)&hv[12] = hp[3];
                    }

                    #pragma unroll
                    for (int j = 0; j < HID; ++j) CH(a_rec, hs[j], wr[j]);

                    if (l == 0) {
                        a_in = b2f(pan_c[d]);
                    } else {
                        #pragma unroll
                        for (int j = 0; j < HID; ++j) CH(a_in, hv[j], wi[j]);
                    }

                    const float z = bfr(bfr(a_in + a_rec) + bias_);
                    const float a = tg ? tanh_np(z) : sig_np(z);

                    const float fv = __shfl(a, (lane + 15) & 63);
                    const float gv = __shfl(a, (lane + 30) & 63);
                    const float ov = __shfl(a, (lane + 45) & 63);

                    const float cn = bfr(bfr(fv * c_) + bfr(a * gv));
                    c_ = cn;
                    const float hn = bfr(ov * tanh_np(cn));

                    #pragma unroll
                    for (int j = 0; j < HID; ++j)
                        hs[j] = __uint_as_float(__builtin_amdgcn_readlane(__float_as_uint(hn), j));

                    if (l < NLAY - 1 && lane < HID) ring[l][t & (RS-1)][lane] = hn;
                    if (l == NLAY - 1 && t == len - 1 && lane < HID)
                        out[s * HID + lane] = hn;
                }
            }
        }
        __syncthreads();                     // one barrier per group
    }
}

// ============ Fallback (round-6, passing): used if ws too small ============
__global__ __launch_bounds__(64, 1)
void lstm4_bf16np(const float* __restrict__ emb,
                  const int*   __restrict__ lengths,
                  const float* __restrict__ Wih0,
                  const float* __restrict__ Wihr,
                  const float* __restrict__ Whh,
                  const float* __restrict__ bih,
                  const float* __restrict__ bhh,
                  float* __restrict__ out)
{
    const int s    = blockIdx.x;
    const int lane = threadIdx.x;
    const int g    = (lane < NG) ? lane : (NG - 1);

    __shared__ __align__(16) float x_lds[DIM];
    __shared__ __align__(16) float h_lds[NLAY][16];

    float wx[DIM];
    #pragma unroll
    for (int q = 0; q < DIM/4; ++q) {
        float4 w = *(const float4*)(Wih0 + g*DIM + 4*q);
        wx[4*q+0] = bfr(w.x); wx[4*q+1] = bfr(w.y);
        wx[4*q+2] = bfr(w.z); wx[4*q+3] = bfr(w.w);
    }
    float wr[NLAY][16]; float wi[NLAY-1][16]; float bias[NLAY];
    #pragma unroll
    for (int l = 0; l < NLAY; ++l) {
        #pragma unroll
        for (int j = 0; j < HID; ++j) wr[l][j] = bfr(Whh[(l*NG + g)*HID + j]);
        wr[l][15] = 0.0f;
        bias[l] = bfr(bfr(bih[l*NG + g]) + bfr(bhh[l*NG + g]));
    }
    #pragma unroll
    for (int l = 0; l < NLAY-1; ++l) {
        #pragma unroll
        for (int j = 0; j < HID; ++j) wi[l][j] = bfr(Wihr[(l*NG + g)*HID + j]);
        wi[l][15] = 0.0f;
    }
    if (lane < 16) {
        #pragma unroll
        for (int l = 0; l < NLAY; ++l) h_lds[l][lane] = 0.0f;
    }
    float c[NLAY] = {0.0f, 0.0f, 0.0f, 0.0f};
    int len = lengths[s];
    len = len < 1 ? 1 : (len > T2 ? T2 : len);
    const float* xb = emb + (size_t)s * T2 * DIM;
    x_lds[lane] = bfr(xb[lane]);
    __syncthreads();
    const bool tg = (lane >= 30 && lane < 45);
    const float4* x4 = (const float4*)x_lds;
    float hout = 0.0f;
    for (int t = 0; t < len; ++t) {
        const int tn = (t + 1 < len) ? (t + 1) : t;
        const float xn = bfr(xb[(size_t)tn * DIM + lane]);
        #pragma unroll
        for (int l = 0; l < NLAY; ++l) {
            float a_in = 0.0f;
            if (l == 0) {
                #pragma unroll
                for (int q = 0; q < 16; ++q) {
                    float4 v = x4[q];
                    CH(a_in, v.x, wx[4*q+0]); CH(a_in, v.y, wx[4*q+1]);
                    CH(a_in, v.z, wx[4*q+2]); CH(a_in, v.w, wx[4*q+3]);
                }
            } else {
                const float4* hp = (const float4*)h_lds[l-1];
                float hv[16];
                *(float4*)&hv[0]  = hp[0]; *(float4*)&hv[4]  = hp[1];
                *(float4*)&hv[8]  = hp[2]; *(float4*)&hv[12] = hp[3];
                #pragma unroll
                for (int j = 0; j < HID; ++j) CH(a_in, hv[j], wi[l-1][j]);
            }
            float a_rec = 0.0f;
            {
                const float4* hc = (const float4*)h_lds[l];
                float hv[16];
                *(float4*)&hv[0]  = hc[0]; *(float4*)&hv[4]  = hc[1];
                *(float4*)&hv[8]  = hc[2]; *(float4*)&hv[12] = hc[3];
                #pragma unroll
                for (int j = 0; j < HID; ++j) CH(a_rec, hv[j], wr[l][j]);
            }
            const float z = bfr(bfr(a_in + a_rec) + bias[l]);
            const float a = tg ? tanh_np(z) : sig_np(z);
            const float fv = __shfl(a, (lane + 15) & 63);
            const float gv = __shfl(a, (lane + 30) & 63);
            const float ov = __shfl(a, (lane + 45) & 63);
            const float cn = bfr(bfr(fv * c[l]) + bfr(a * gv));
            c[l] = cn;
            const float hn = bfr(ov * tanh_np(cn));
            if (lane < HID) h_lds[l][lane] = hn;
            if (l == NLAY-1 && t == len-1) hout = hn;
        }
        x_lds[lane] = xn;
    }
    if (lane < HID) out[s * HID + lane] = hout;
}

extern "C" void kernel_launch(void* const* d_in, const int* in_sizes, int n_in,
                              void* d_out, int out_size, void* d_ws, size_t ws_size,
                              hipStream_t stream) {
    const float* emb     = (const float*)d_in[0];
    const int*   lengths = (const int*)  d_in[1];
    const float* Wih0    = (const float*)d_in[2];
    const float* Wihr    = (const float*)d_in[3];
    const float* Whh     = (const float*)d_in[4];
    const float* bih     = (const float*)d_in[5];
    const float* bhh     = (const float*)d_in[6];
    float* out = (float*)d_out;

    const size_t need = (size_t)BSZ * T2 * NG * sizeof(unsigned short);
    if (ws_size >= need) {
        unsigned short* pa = (unsigned short*)d_ws;
        proj0<<<2048, 256, 0, stream>>>(emb, lengths, Wih0, pa);
        lstm4_pipe<<<BSZ, 256, 0, stream>>>(lengths, pa, Wihr, Whh, bih, bhh, out);
    } else {
        lstm4_bf16np<<<BSZ, 64, 0, stream>>>(emb, lengths, Wih0, Wihr, Whh, bih, bhh, out);
    }
}